// Round 4
// baseline (443.631 us; speedup 1.0000x reference)
//
#include <hip/hip_runtime.h>
#include <math.h>

#define HW   56
#define DIMC 256
#define HID  1024

typedef __attribute__((ext_vector_type(8))) short bf16x8;
typedef __attribute__((ext_vector_type(4))) float f32x4;

__device__ __forceinline__ short f2bf(float f) {
  union { float fv; unsigned u; } v; v.fv = f;
  unsigned r = v.u + 0x7fffu + ((v.u >> 16) & 1u);
  return (short)(r >> 16);
}
__device__ __forceinline__ float bf2f(short s) {
  union { unsigned u; float fv; } v; v.u = ((unsigned)(unsigned short)s) << 16;
  return v.fv;
}
// gelu via sigmoid: v*sigmoid(1.702v). rcp (1-ulp approx) fine: error scaled
// by gamma=1e-6 before reaching the output.
__device__ __forceinline__ float gelu_fast(float v) {
  float e = exp2f(-2.4556260f * v);
  return v * __builtin_amdgcn_rcpf(1.f + e);
}
// pack 8 f32 -> 8 OCP e4m3 bytes in one i64 (byte j = value j; A and B use the
// same j-indexing so any HW k-permutation within the 8-group cancels in MFMA).
__device__ __forceinline__ long pk8(float f0, float f1, float f2, float f3,
                                    float f4, float f5, float f6, float f7) {
  int lo = __builtin_amdgcn_cvt_pk_fp8_f32(f0, f1, 0, false);
  lo = __builtin_amdgcn_cvt_pk_fp8_f32(f2, f3, lo, true);
  int hi = __builtin_amdgcn_cvt_pk_fp8_f32(f4, f5, 0, false);
  hi = __builtin_amdgcn_cvt_pk_fp8_f32(f6, f7, hi, true);
  return ((long)(unsigned)lo) | ((long)hi << 32);
}
__device__ __forceinline__ char f2fp8(float f) {
  return (char)(__builtin_amdgcn_cvt_pk_fp8_f32(f, f, 0, false) & 0xff);
}

// ---------------------------------------------------------------------------
// prep_pack: weights -> fp8 MFMA-fragment-major (frag = 64 lanes x 8B = 512B).
// Thread g==0 also zeroes the work-queue counters (re-zeroed every launch).
// ---------------------------------------------------------------------------
__global__ void prep_pack(const float* __restrict__ w1, const float* __restrict__ w2,
                          long* __restrict__ w1p, long* __restrict__ w2p,
                          int* __restrict__ qmeta) {
  int g = blockIdx.x * 256 + threadIdx.x;
  if (g == 0) { qmeta[0] = 0; qmeta[1] = 0; qmeta[2] = 0; }
  int f = g >> 6, lane = g & 63;
  int l15 = lane & 15, q = lane >> 4;
  float t[8];
  if (f < 512) {
    int k8 = f & 7, tt = f >> 3, nt = tt & 1, ch = tt >> 1;
    int n = ch * 32 + nt * 16 + l15;
    int k = k8 * 32 + q * 8;
    #pragma unroll
    for (int j = 0; j < 8; ++j) t[j] = w1[(k + j) * HID + n];
    w1p[f * 64 + lane] = pk8(t[0], t[1], t[2], t[3], t[4], t[5], t[6], t[7]);
  } else {
    int f2 = f - 512;
    int nt2 = f2 & 15, ch = f2 >> 4;
    int k = ch * 32 + q * 8;
    int c = nt2 * 16 + l15;
    #pragma unroll
    for (int j = 0; j < 8; ++j) t[j] = w2[(k + j) * DIMC + c];
    w2p[f2 * 64 + lane] = pk8(t[0], t[1], t[2], t[3], t[4], t[5], t[6], t[7]);
  }
}

// ---------------------------------------------------------------------------
// compact_k: dense active-tile list. qmeta[0]=count, [1]=mlp head, [2]=conv
// head, list at qmeta+16.
// ---------------------------------------------------------------------------
__global__ void compact_k(const int* __restrict__ mask, int* __restrict__ qmeta) {
  int t = blockIdx.x * 256 + threadIdx.x;
  if (t < 1568 && mask[t]) {
    int i = atomicAdd(qmeta, 1);
    qmeta[16 + i] = t;
  }
}

// ---------------------------------------------------------------------------
// conv_k v3: persistent blocks popping (tile,cgi) units off the queue.
// 16-channel groups, LDS 22400 B + queue slot; launch 1024 = 4 blocks/CU.
// ---------------------------------------------------------------------------
__global__ __launch_bounds__(256, 4) void conv_k(
    const float* __restrict__ x, const float* __restrict__ dw_w,
    const float* __restrict__ dw_b, int* __restrict__ qmeta,
    short* __restrict__ ybuf) {
  __shared__ __align__(16) float s_patch[16 * 14 * 20];   // 22400 B
  __shared__ int s_u;
  short* s_yout = (short*)s_patch;                        // alias (2048 B)
  const int* list = qmeta + 16;
  int tid = threadIdx.x;
  int total = qmeta[0] * 16;

  for (;;) {
    if (tid == 0) s_u = atomicAdd(qmeta + 2, 1);
    __syncthreads();
    int u = s_u;
    if (u >= total) break;
    int tile = list[u >> 4], cgi = u & 15;
    int wb = tile % 7; int t2 = tile / 7; int hb = t2 % 7; int b = t2 / 7;
    int h0 = hb * 8, w0 = wb * 8, cg0 = cgi * 16;

    // 16c x 14r x 4 vec-slots = 896 slots
    #pragma unroll
    for (int it = 0; it < 4; ++it) {
      int slot = tid + 256 * it;
      if (slot < 896) {
        int j = slot & 3, row = slot >> 2;    // row = c*14 + r
        int c = row / 14, r = row - c * 14;
        int gh = h0 - 3 + r;
        f32x4 v = (f32x4){0.f, 0.f, 0.f, 0.f};
        bool ok = (gh >= 0) && (gh < HW) && !(wb == 0 && j == 0) && !(wb == 6 && j == 3);
        if (ok)
          v = *(const f32x4*)(x + ((long)(b * DIMC + cg0 + c) * HW + gh) * HW + (w0 - 4) + 4 * j);
        *(f32x4*)(s_patch + c * 280 + r * 20 + 4 * j) = v;
      }
    }

    int cl = tid >> 4, s = tid & 15;
    int wq = s & 7, hf = s >> 3;              // 4 output rows: h = hf*4 + 0..3
    float wt[49];
    #pragma unroll
    for (int j = 0; j < 49; ++j) wt[j] = dw_w[(cg0 + cl) * 49 + j];
    __syncthreads();

    float y[4] = {0.f, 0.f, 0.f, 0.f};
    #pragma unroll
    for (int rr = 0; rr < 10; ++rr) {         // rows hf*4 .. hf*4+9
      float row[7];
      #pragma unroll
      for (int j = 0; j < 7; ++j) row[j] = s_patch[cl * 280 + (hf * 4 + rr) * 20 + wq + 1 + j];
      #pragma unroll
      for (int dy = 0; dy < 7; ++dy) {
        int hh = rr - dy;
        if (hh >= 0 && hh < 4) {
          #pragma unroll
          for (int dx = 0; dx < 7; ++dx) y[hh] += row[dx] * wt[dy * 7 + dx];
        }
      }
    }
    float db = dw_b[cg0 + cl];
    __syncthreads();                          // all patch reads done (alias!)
    #pragma unroll
    for (int hh = 0; hh < 4; ++hh)
      s_yout[cl * 64 + (hf * 4 + hh) * 8 + wq] = f2bf(y[hh] + db);
    __syncthreads();

    if (tid < 128) {
      int c = tid >> 3, pd = (tid & 7) * 8;
      bf16x8 v = *(const bf16x8*)(s_yout + c * 64 + pd);
      *(bf16x8*)(ybuf + ((long)tile * DIMC + cg0 + c) * 64 + pd) = v;
    }
    __syncthreads();                          // protect s_patch/s_yout + s_u
  }
}

// ---------------------------------------------------------------------------
// mlp_k v6: R1's proven per-tile body (fp8 MFMA, LDS bf16 staging transpose,
// vectorized LN) wrapped in a persistent work-queue loop. Grid 768 = exactly
// 3 blocks/CU (LDS 46592 B); queue guarantees even CU load + no dead blocks.
// ---------------------------------------------------------------------------
__global__ __launch_bounds__(256, 3) void mlp_k(
    const float* __restrict__ ln_w, const float* __restrict__ ln_b,
    const float* __restrict__ b1v, const float* __restrict__ b2v,
    const float* __restrict__ gammav,
    const long* __restrict__ w1p, const long* __restrict__ w2p,
    int* __restrict__ qmeta, short* __restrict__ ybuf) {
  __shared__ __align__(16) char smem[46592];
  __shared__ int s_u;
  short* s_a   = (short*)smem;                  // [p 64][264] bf16 (LN'd A)
  short* s_del = (short*)smem;                  // alias: [c 256][72] bf16
  char*  s_h8  = smem + 36864;                  // 2 x [64 m][40] fp8
  float* s_p1  = (float*)(smem + 41984);
  float* s_p2  = (float*)(smem + 43008);
  float* s_mu  = (float*)(smem + 44032);
  float* s_rs  = (float*)(smem + 44288);
  float* s_lnw = (float*)(smem + 44544);
  float* s_lnb = (float*)(smem + 45568);

  const int* list = qmeta + 16;
  int tid = threadIdx.x;
  int total = qmeta[0];

  s_lnw[tid] = ln_w[tid];
  s_lnb[tid] = ln_b[tid];

  const int wv = tid >> 6, lane = tid & 63;
  const int l15 = lane & 15, q = lane >> 4;
  const int mh = wv & 1, nh = wv >> 1;          // GEMM1: 2M x 2N wave split

  for (;;) {
    if (tid == 0) s_u = atomicAdd(qmeta + 1, 1);
    __syncthreads();                            // also covers s_lnw/prev-iter
    int i = s_u;
    if (i >= total) break;
    int tile = list[i];
    short* ytile = ybuf + (long)tile * DIMC * 64;

    // load ybuf [c][p] -> transpose into s_a [p][c]; lane-per-channel so the
    // scalar u16 LDS writes spread across banks (c consecutive per lane).
    #pragma unroll
    for (int k = 0; k < 8; ++k) {
      int q4 = tid + 256 * k;
      int c = q4 & 255, pd = (q4 >> 8) * 8;
      bf16x8 v = *(const bf16x8*)(ytile + c * 64 + pd);
      #pragma unroll
      for (int j = 0; j < 8; ++j) s_a[(pd + j) * 264 + c] = v[j];
    }
    __syncthreads();

    // LN stats via vector reads, values kept in registers for the normalize
    {
      int p = tid & 63, cq = tid >> 6;
      bf16x8 va[8];
      float s1 = 0.f, s2 = 0.f;
      #pragma unroll
      for (int ii = 0; ii < 8; ++ii) {
        va[ii] = *(const bf16x8*)(s_a + p * 264 + cq * 64 + ii * 8);
        #pragma unroll
        for (int j = 0; j < 8; ++j) {
          float f = bf2f(va[ii][j]);
          s1 += f; s2 += f * f;
        }
      }
      s_p1[cq * 64 + p] = s1; s_p2[cq * 64 + p] = s2;
      __syncthreads();
      if (tid < 64) {
        float t1 = s_p1[tid] + s_p1[64 + tid] + s_p1[128 + tid] + s_p1[192 + tid];
        float t2 = s_p2[tid] + s_p2[64 + tid] + s_p2[128 + tid] + s_p2[192 + tid];
        float mu = t1 * (1.f / 256.f);
        float var = t2 * (1.f / 256.f) - mu * mu;
        s_mu[tid] = mu; s_rs[tid] = rsqrtf(var + 1e-6f);
      }
      __syncthreads();
      float mu = s_mu[p], rs = s_rs[p];
      #pragma unroll
      for (int ii = 0; ii < 8; ++ii) {
        int c0 = cq * 64 + ii * 8;
        bf16x8 v = va[ii];
        #pragma unroll
        for (int j = 0; j < 8; ++j)
          v[j] = f2bf((bf2f(v[j]) - mu) * rs * s_lnw[c0 + j] + s_lnb[c0 + j]);
        *(bf16x8*)(s_a + p * 264 + c0) = v;
      }
    }
    __syncthreads();

    // hoist the loop-invariant GEMM1 A-operand into fp8 registers (32 VGPRs)
    const short* aRow0 = s_a + (32 * mh + l15) * 264 + q * 8;
    const short* aRow1 = s_a + (32 * mh + 16 + l15) * 264 + q * 8;
    long a0f[8], a1f[8];
    #pragma unroll
    for (int k8 = 0; k8 < 8; ++k8) {
      bf16x8 v0 = *(const bf16x8*)(aRow0 + k8 * 32);
      bf16x8 v1 = *(const bf16x8*)(aRow1 + k8 * 32);
      a0f[k8] = pk8(bf2f(v0[0]), bf2f(v0[1]), bf2f(v0[2]), bf2f(v0[3]),
                    bf2f(v0[4]), bf2f(v0[5]), bf2f(v0[6]), bf2f(v0[7]));
      a1f[k8] = pk8(bf2f(v1[0]), bf2f(v1[1]), bf2f(v1[2]), bf2f(v1[3]),
                    bf2f(v1[4]), bf2f(v1[5]), bf2f(v1[6]), bf2f(v1[7]));
    }

    f32x4 z[4][4];                              // [jt][Mt], c = wv*64+jt*16+l15
    #pragma unroll
    for (int jt = 0; jt < 4; ++jt)
      #pragma unroll
      for (int Mt = 0; Mt < 4; ++Mt) z[jt][Mt] = (f32x4){0.f, 0.f, 0.f, 0.f};

    long w1r[8];                                // prefetched W1 frags (ch=0)
    #pragma unroll
    for (int k8 = 0; k8 < 8; ++k8)
      w1r[k8] = w1p[(long)(nh * 8 + k8) * 64 + lane];

    for (int ch = 0; ch < 32; ++ch) {
      long w2r[4];
      #pragma unroll
      for (int jt = 0; jt < 4; ++jt)
        w2r[jt] = w2p[(long)(ch * 16 + wv * 4 + jt) * 64 + lane];
      float bb = b1v[ch * 32 + 16 * nh + l15];

      f32x4 acc0 = (f32x4){0.f, 0.f, 0.f, 0.f};
      f32x4 acc1 = (f32x4){0.f, 0.f, 0.f, 0.f};
      __builtin_amdgcn_s_setprio(1);
      #pragma unroll
      for (int k8 = 0; k8 < 8; ++k8) {
        acc0 = __builtin_amdgcn_mfma_f32_16x16x32_fp8_fp8(a0f[k8], w1r[k8], acc0, 0, 0, 0);
        acc1 = __builtin_amdgcn_mfma_f32_16x16x32_fp8_fp8(a1f[k8], w1r[k8], acc1, 0, 0, 0);
      }
      __builtin_amdgcn_s_setprio(0);
      long w1n[8];                              // prefetch next chunk's W1
      if (ch < 31) {
        #pragma unroll
        for (int k8 = 0; k8 < 8; ++k8)
          w1n[k8] = w1p[(long)(((ch + 1) * 2 + nh) * 8 + k8) * 64 + lane];
      }
      char* hb = s_h8 + (ch & 1) * 2560;
      #pragma unroll
      for (int r = 0; r < 4; ++r) {
        hb[(32 * mh + 4 * q + r) * 40 + 16 * nh + l15]      = f2fp8(gelu_fast(acc0[r] + bb));
        hb[(32 * mh + 16 + 4 * q + r) * 40 + 16 * nh + l15] = f2fp8(gelu_fast(acc1[r] + bb));
      }
      __syncthreads();                          // h[ch&1] complete
      __builtin_amdgcn_s_setprio(1);
      #pragma unroll
      for (int Mt = 0; Mt < 4; ++Mt) {
        long aH = *(const long*)(hb + (16 * Mt + l15) * 40 + q * 8);
        #pragma unroll
        for (int jt = 0; jt < 4; ++jt)
          z[jt][Mt] = __builtin_amdgcn_mfma_f32_16x16x32_fp8_fp8(aH, w2r[jt], z[jt][Mt], 0, 0, 0);
      }
      __builtin_amdgcn_s_setprio(0);
      if (ch < 31) {
        #pragma unroll
        for (int k8 = 0; k8 < 8; ++k8) w1r[k8] = w1n[k8];
      }
    }

    // epilogue: delta = (z+b2)*gamma -> s_del [c][72] -> ybuf in place
    #pragma unroll
    for (int jt = 0; jt < 4; ++jt) {
      int c = wv * 64 + jt * 16 + l15;
      float bb = b2v[c], gm = gammav[c];
      #pragma unroll
      for (int Mt = 0; Mt < 4; ++Mt) {
        #pragma unroll
        for (int r = 0; r < 4; ++r)
          s_del[c * 72 + 16 * Mt + 4 * q + r] = f2bf((z[jt][Mt][r] + bb) * gm);
      }
    }
    __syncthreads();
    #pragma unroll
    for (int k = 0; k < 8; ++k) {
      int q4 = tid + 256 * k;
      int c = q4 & 255, pd = (q4 >> 8) * 8;
      bf16x8 v = *(const bf16x8*)(s_del + c * 72 + pd);
      *(bf16x8*)(ytile + c * 64 + pd) = v;
    }
    __syncthreads();                            // s_del reads done before next
  }
}

// ---------------------------------------------------------------------------
// epi_k: dense, fully coalesced. out = x + (active ? delta : 0).
// ---------------------------------------------------------------------------
__global__ __launch_bounds__(256) void epi_k(
    const float* __restrict__ x, const int* __restrict__ mask,
    const short* __restrict__ delta, float* __restrict__ out) {
  const int NU = 32 * DIMC * HW * 7;            // units of 8 floats
  int stride = gridDim.x * 256;
  for (int u = blockIdx.x * 256 + threadIdx.x; u < NU; u += stride) {
    int wb = u % 7; int t1 = u / 7;
    int h = t1 % 56; int t2 = t1 / 56;
    int c = t2 & 255; int b = t2 >> 8;
    int g = ((b * DIMC + c) * HW + h) * HW + wb * 8;
    f32x4 x0 = *(const f32x4*)(x + g);
    f32x4 x1 = *(const f32x4*)(x + g + 4);
    int tile = (b * 7 + (h >> 3)) * 7 + wb;
    if (mask[tile]) {
      bf16x8 d = *(const bf16x8*)(delta + ((long)tile * DIMC + c) * 64 + (h & 7) * 8);
      #pragma unroll
      for (int i = 0; i < 4; ++i) { x0[i] += bf2f(d[i]); x1[i] += bf2f(d[4 + i]); }
    }
    *(f32x4*)(out + g) = x0;
    *(f32x4*)(out + g + 4) = x1;
  }
}

extern "C" void kernel_launch(void* const* d_in, const int* in_sizes, int n_in,
                              void* d_out, int out_size, void* d_ws, size_t ws_size,
                              hipStream_t stream) {
  const float* x    = (const float*)d_in[0];
  const int*   mask = (const int*)d_in[1];
  const float* dw_w = (const float*)d_in[2];
  const float* dw_b = (const float*)d_in[3];
  const float* ln_w = (const float*)d_in[4];
  const float* ln_b = (const float*)d_in[5];
  const float* w1   = (const float*)d_in[6];
  const float* b1   = (const float*)d_in[7];
  const float* w2   = (const float*)d_in[8];
  const float* b2   = (const float*)d_in[9];
  const float* gm   = (const float*)d_in[10];
  float* out = (float*)d_out;

  long* w1p  = (long*)d_ws;                     // 256 KB (512 frags x 512B)
  long* w2p  = w1p + 512 * 64;                  // 256 KB
  int*  qmeta = (int*)(w2p + 512 * 64);         // 8 KB: counters + tile list
  short* ybuf = (short*)((char*)qmeta + 8192);  // 51.4 MB

  prep_pack<<<256, 256, 0, stream>>>(w1, w2, w1p, w2p, qmeta);
  compact_k<<<7, 256, 0, stream>>>(mask, qmeta);
  conv_k<<<1024, 256, 0, stream>>>(x, dw_w, dw_b, qmeta, ybuf);
  mlp_k<<<768, 256, 0, stream>>>(ln_w, ln_b, b1, b2, gm, w1p, w2p, qmeta, ybuf);
  epi_k<<<4096, 256, 0, stream>>>(x, mask, ybuf, out);
}

// Round 5
// 350.245 us; speedup vs baseline: 1.2666x; 1.2666x over previous
//
#include <hip/hip_runtime.h>
#include <math.h>

#define HW   56
#define DIMC 256
#define HID  1024

typedef __attribute__((ext_vector_type(8))) short bf16x8;
typedef __attribute__((ext_vector_type(4))) float f32x4;

__device__ __forceinline__ short f2bf(float f) {
  union { float fv; unsigned u; } v; v.fv = f;
  unsigned r = v.u + 0x7fffu + ((v.u >> 16) & 1u);
  return (short)(r >> 16);
}
__device__ __forceinline__ float bf2f(short s) {
  union { unsigned u; float fv; } v; v.u = ((unsigned)(unsigned short)s) << 16;
  return v.fv;
}
// gelu via sigmoid: v*sigmoid(1.702v). rcp (1-ulp approx) fine: error scaled
// by gamma=1e-6 before reaching the output.
__device__ __forceinline__ float gelu_fast(float v) {
  float e = exp2f(-2.4556260f * v);
  return v * __builtin_amdgcn_rcpf(1.f + e);
}
// pack 8 f32 -> 8 OCP e4m3 bytes in one i64 (byte j = value j; A and B use the
// same j-indexing so any HW k-permutation within the 8-group cancels in MFMA).
__device__ __forceinline__ long pk8(float f0, float f1, float f2, float f3,
                                    float f4, float f5, float f6, float f7) {
  int lo = __builtin_amdgcn_cvt_pk_fp8_f32(f0, f1, 0, false);
  lo = __builtin_amdgcn_cvt_pk_fp8_f32(f2, f3, lo, true);
  int hi = __builtin_amdgcn_cvt_pk_fp8_f32(f4, f5, 0, false);
  hi = __builtin_amdgcn_cvt_pk_fp8_f32(f6, f7, hi, true);
  return ((long)(unsigned)lo) | ((long)hi << 32);
}
__device__ __forceinline__ char f2fp8(float f) {
  return (char)(__builtin_amdgcn_cvt_pk_fp8_f32(f, f, 0, false) & 0xff);
}

// ---------------------------------------------------------------------------
// prep_pack: weights -> fp8 MFMA-fragment-major (frag = 64 lanes x 8B = 512B).
// Thread g==0 also zeroes the work-queue counters (re-zeroed every launch).
// ---------------------------------------------------------------------------
__global__ void prep_pack(const float* __restrict__ w1, const float* __restrict__ w2,
                          long* __restrict__ w1p, long* __restrict__ w2p,
                          int* __restrict__ qmeta) {
  int g = blockIdx.x * 256 + threadIdx.x;
  if (g == 0) { qmeta[0] = 0; qmeta[1] = 0; qmeta[2] = 0; }
  int f = g >> 6, lane = g & 63;
  int l15 = lane & 15, q = lane >> 4;
  float t[8];
  if (f < 512) {
    int k8 = f & 7, tt = f >> 3, nt = tt & 1, ch = tt >> 1;
    int n = ch * 32 + nt * 16 + l15;
    int k = k8 * 32 + q * 8;
    #pragma unroll
    for (int j = 0; j < 8; ++j) t[j] = w1[(k + j) * HID + n];
    w1p[f * 64 + lane] = pk8(t[0], t[1], t[2], t[3], t[4], t[5], t[6], t[7]);
  } else {
    int f2 = f - 512;
    int nt2 = f2 & 15, ch = f2 >> 4;
    int k = ch * 32 + q * 8;
    int c = nt2 * 16 + l15;
    #pragma unroll
    for (int j = 0; j < 8; ++j) t[j] = w2[(k + j) * DIMC + c];
    w2p[f2 * 64 + lane] = pk8(t[0], t[1], t[2], t[3], t[4], t[5], t[6], t[7]);
  }
}

// ---------------------------------------------------------------------------
// compact_k: dense active-tile list. qmeta[0]=count, [1]=mlp head, list at +16.
// ---------------------------------------------------------------------------
__global__ void compact_k(const int* __restrict__ mask, int* __restrict__ qmeta) {
  int t = blockIdx.x * 256 + threadIdx.x;
  if (t < 1568 && mask[t]) {
    int i = atomicAdd(qmeta, 1);
    qmeta[16 + i] = t;
  }
}

// ---------------------------------------------------------------------------
// conv_k v4: DENSE per-(b,c) plane. x is read exactly once, full 224B rows,
// perfectly coalesced (R3 counters: tile-halo scheme fetched 184MB in 64B
// segments at 16% BW). Plane + zero halo in LDS [62][64]f32; each thread does
// 2 cols x 7 rows with a mod-7 rolling register window (fully unrolled =>
// static indexing); weights in SGPRs (uniform per block); per-row mask skip;
// output staged [56][64]bf16 and written 128B-contiguous per active tile.
// LDS 23040B, ~100 VGPR -> 4 waves/SIMD.
// ---------------------------------------------------------------------------
__global__ __launch_bounds__(256, 4) void conv_k(
    const float* __restrict__ x, const int* __restrict__ mask,
    const float* __restrict__ dw_w, const float* __restrict__ dw_b,
    short* __restrict__ ybuf) {
  __shared__ __align__(16) float s_plane[62 * 64];        // 15872 B
  __shared__ __align__(16) short s_out[56 * 64];          // 7168 B

  int bid = blockIdx.x;
  int c = bid & 255, b = bid >> 8;
  int tid = threadIdx.x;
  const float* xp = x + (long)(b * DIMC + c) * HW * HW;

  // stage plane with zero halo: input rows -3..58 -> LDS 0..61, cols -4..59 -> 0..63
  #pragma unroll
  for (int it = 0; it < 4; ++it) {
    int slot = tid + 256 * it;
    if (slot < 992) {
      int row = slot >> 4, jj = slot & 15;
      f32x4 v = (f32x4){0.f, 0.f, 0.f, 0.f};
      if (row >= 3 && row < 59 && jj >= 1 && jj <= 14)
        v = *(const f32x4*)(xp + (row - 3) * HW + (jj * 4 - 4));
      *(f32x4*)(s_plane + row * 64 + jj * 4) = v;
    }
  }

  // weights -> SGPRs (uniform across block: one channel per block)
  float wt[49];
  #pragma unroll
  for (int j = 0; j < 49; ++j) {
    int wi = __builtin_amdgcn_readfirstlane(__builtin_bit_cast(int, dw_w[c * 49 + j]));
    wt[j] = __builtin_bit_cast(float, wi);
  }
  float db = dw_b[c];
  __syncthreads();

  int cp = tid & 31, rg = tid >> 5;             // col-pair, row-group (7 rows)
  if (cp < 28) {
    int col0 = cp * 2, wb = col0 >> 3;
    int r0 = rg * 7;                            // r0 % 7 == 0 -> static slots
    int mrow = 0;
    #pragma unroll
    for (int hb = 0; hb < 7; ++hb)
      mrow |= (mask[(b * 7 + hb) * 7 + wb] ? 1 : 0) << hb;
    int hb1 = r0 >> 3, hb2 = (r0 + 6) >> 3;
    if (mrow & ((2 << hb2) - (1 << hb1))) {
      float W[7][10];                           // rolling window, static idx
#define LDROW(S, LR) do { int _o = (LR) * 64 + col0;                         \
      W[S][0] = s_plane[_o + 0]; W[S][1] = s_plane[_o + 1];                  \
      W[S][2] = s_plane[_o + 2]; W[S][3] = s_plane[_o + 3];                  \
      W[S][4] = s_plane[_o + 4]; W[S][5] = s_plane[_o + 5];                  \
      W[S][6] = s_plane[_o + 6]; W[S][7] = s_plane[_o + 7];                  \
      W[S][8] = s_plane[_o + 8]; W[S][9] = s_plane[_o + 9]; } while (0)
      // prologue: LDS rows r0..r0+5 into slots 0..5
      LDROW(0, r0 + 0); LDROW(1, r0 + 1); LDROW(2, r0 + 2);
      LDROW(3, r0 + 3); LDROW(4, r0 + 4); LDROW(5, r0 + 5);
      #pragma unroll
      for (int k = 0; k < 7; ++k) {
        LDROW((6 + k) % 7, r0 + 6 + k);
        int r = r0 + k;
        if ((mrow >> (r >> 3)) & 1) {
          float out0 = 0.f, out1 = 0.f;
          #pragma unroll
          for (int dy = 0; dy < 7; ++dy) {
            const float* wr = wt + dy * 7;
            const float* ww = W[(k + dy) % 7];
            #pragma unroll
            for (int dx = 0; dx < 7; ++dx) {
              out0 += wr[dx] * ww[1 + dx];
              out1 += wr[dx] * ww[2 + dx];
            }
          }
          unsigned pk = (unsigned)(unsigned short)f2bf(out0 + db)
                      | ((unsigned)(unsigned short)f2bf(out1 + db) << 16);
          ((int*)s_out)[r * 32 + cp] = (int)pk;
        }
      }
#undef LDROW
    }
  }
  __syncthreads();

  // write active tiles: 49 tiles x 8 rows = 392 bf16x8 units, 128B contiguous
  #pragma unroll
  for (int it = 0; it < 2; ++it) {
    int u = tid + 256 * it;
    if (u < 392) {
      int hh = u & 7, th = u >> 3;
      int hbL = th / 7, wbL = th % 7;
      int tile = (b * 7 + hbL) * 7 + wbL;
      if (mask[tile]) {
        bf16x8 v = *(const bf16x8*)(s_out + (hbL * 8 + hh) * 64 + wbL * 8);
        *(bf16x8*)(ybuf + ((long)tile * DIMC + c) * 64 + hh * 8) = v;
      }
    }
  }
}

// ---------------------------------------------------------------------------
// mlp_k v6 (unchanged from R3): R1's per-tile body (fp8 MFMA, LDS bf16
// staging transpose, vectorized LN) in a persistent work-queue loop.
// ---------------------------------------------------------------------------
__global__ __launch_bounds__(256, 3) void mlp_k(
    const float* __restrict__ ln_w, const float* __restrict__ ln_b,
    const float* __restrict__ b1v, const float* __restrict__ b2v,
    const float* __restrict__ gammav,
    const long* __restrict__ w1p, const long* __restrict__ w2p,
    int* __restrict__ qmeta, short* __restrict__ ybuf) {
  __shared__ __align__(16) char smem[46592];
  __shared__ int s_u;
  short* s_a   = (short*)smem;                  // [p 64][264] bf16 (LN'd A)
  short* s_del = (short*)smem;                  // alias: [c 256][72] bf16
  char*  s_h8  = smem + 36864;                  // 2 x [64 m][40] fp8
  float* s_p1  = (float*)(smem + 41984);
  float* s_p2  = (float*)(smem + 43008);
  float* s_mu  = (float*)(smem + 44032);
  float* s_rs  = (float*)(smem + 44288);
  float* s_lnw = (float*)(smem + 44544);
  float* s_lnb = (float*)(smem + 45568);

  const int* list = qmeta + 16;
  int tid = threadIdx.x;
  int total = qmeta[0];

  s_lnw[tid] = ln_w[tid];
  s_lnb[tid] = ln_b[tid];

  const int wv = tid >> 6, lane = tid & 63;
  const int l15 = lane & 15, q = lane >> 4;
  const int mh = wv & 1, nh = wv >> 1;          // GEMM1: 2M x 2N wave split

  for (;;) {
    if (tid == 0) s_u = atomicAdd(qmeta + 1, 1);
    __syncthreads();                            // also covers s_lnw/prev-iter
    int i = s_u;
    if (i >= total) break;
    int tile = list[i];
    short* ytile = ybuf + (long)tile * DIMC * 64;

    // load ybuf [c][p] -> transpose into s_a [p][c]
    #pragma unroll
    for (int k = 0; k < 8; ++k) {
      int q4 = tid + 256 * k;
      int c = q4 & 255, pd = (q4 >> 8) * 8;
      bf16x8 v = *(const bf16x8*)(ytile + c * 64 + pd);
      #pragma unroll
      for (int j = 0; j < 8; ++j) s_a[(pd + j) * 264 + c] = v[j];
    }
    __syncthreads();

    // LN stats via vector reads, values kept in registers for the normalize
    {
      int p = tid & 63, cq = tid >> 6;
      bf16x8 va[8];
      float s1 = 0.f, s2 = 0.f;
      #pragma unroll
      for (int ii = 0; ii < 8; ++ii) {
        va[ii] = *(const bf16x8*)(s_a + p * 264 + cq * 64 + ii * 8);
        #pragma unroll
        for (int j = 0; j < 8; ++j) {
          float f = bf2f(va[ii][j]);
          s1 += f; s2 += f * f;
        }
      }
      s_p1[cq * 64 + p] = s1; s_p2[cq * 64 + p] = s2;
      __syncthreads();
      if (tid < 64) {
        float t1 = s_p1[tid] + s_p1[64 + tid] + s_p1[128 + tid] + s_p1[192 + tid];
        float t2 = s_p2[tid] + s_p2[64 + tid] + s_p2[128 + tid] + s_p2[192 + tid];
        float mu = t1 * (1.f / 256.f);
        float var = t2 * (1.f / 256.f) - mu * mu;
        s_mu[tid] = mu; s_rs[tid] = rsqrtf(var + 1e-6f);
      }
      __syncthreads();
      float mu = s_mu[p], rs = s_rs[p];
      #pragma unroll
      for (int ii = 0; ii < 8; ++ii) {
        int c0 = cq * 64 + ii * 8;
        bf16x8 v = va[ii];
        #pragma unroll
        for (int j = 0; j < 8; ++j)
          v[j] = f2bf((bf2f(v[j]) - mu) * rs * s_lnw[c0 + j] + s_lnb[c0 + j]);
        *(bf16x8*)(s_a + p * 264 + c0) = v;
      }
    }
    __syncthreads();

    // hoist the loop-invariant GEMM1 A-operand into fp8 registers (32 VGPRs)
    const short* aRow0 = s_a + (32 * mh + l15) * 264 + q * 8;
    const short* aRow1 = s_a + (32 * mh + 16 + l15) * 264 + q * 8;
    long a0f[8], a1f[8];
    #pragma unroll
    for (int k8 = 0; k8 < 8; ++k8) {
      bf16x8 v0 = *(const bf16x8*)(aRow0 + k8 * 32);
      bf16x8 v1 = *(const bf16x8*)(aRow1 + k8 * 32);
      a0f[k8] = pk8(bf2f(v0[0]), bf2f(v0[1]), bf2f(v0[2]), bf2f(v0[3]),
                    bf2f(v0[4]), bf2f(v0[5]), bf2f(v0[6]), bf2f(v0[7]));
      a1f[k8] = pk8(bf2f(v1[0]), bf2f(v1[1]), bf2f(v1[2]), bf2f(v1[3]),
                    bf2f(v1[4]), bf2f(v1[5]), bf2f(v1[6]), bf2f(v1[7]));
    }

    f32x4 z[4][4];                              // [jt][Mt], c = wv*64+jt*16+l15
    #pragma unroll
    for (int jt = 0; jt < 4; ++jt)
      #pragma unroll
      for (int Mt = 0; Mt < 4; ++Mt) z[jt][Mt] = (f32x4){0.f, 0.f, 0.f, 0.f};

    long w1r[8];                                // prefetched W1 frags (ch=0)
    #pragma unroll
    for (int k8 = 0; k8 < 8; ++k8)
      w1r[k8] = w1p[(long)(nh * 8 + k8) * 64 + lane];

    for (int ch = 0; ch < 32; ++ch) {
      long w2r[4];
      #pragma unroll
      for (int jt = 0; jt < 4; ++jt)
        w2r[jt] = w2p[(long)(ch * 16 + wv * 4 + jt) * 64 + lane];
      float bb = b1v[ch * 32 + 16 * nh + l15];

      f32x4 acc0 = (f32x4){0.f, 0.f, 0.f, 0.f};
      f32x4 acc1 = (f32x4){0.f, 0.f, 0.f, 0.f};
      __builtin_amdgcn_s_setprio(1);
      #pragma unroll
      for (int k8 = 0; k8 < 8; ++k8) {
        acc0 = __builtin_amdgcn_mfma_f32_16x16x32_fp8_fp8(a0f[k8], w1r[k8], acc0, 0, 0, 0);
        acc1 = __builtin_amdgcn_mfma_f32_16x16x32_fp8_fp8(a1f[k8], w1r[k8], acc1, 0, 0, 0);
      }
      __builtin_amdgcn_s_setprio(0);
      long w1n[8];                              // prefetch next chunk's W1
      if (ch < 31) {
        #pragma unroll
        for (int k8 = 0; k8 < 8; ++k8)
          w1n[k8] = w1p[(long)(((ch + 1) * 2 + nh) * 8 + k8) * 64 + lane];
      }
      char* hb = s_h8 + (ch & 1) * 2560;
      #pragma unroll
      for (int r = 0; r < 4; ++r) {
        hb[(32 * mh + 4 * q + r) * 40 + 16 * nh + l15]      = f2fp8(gelu_fast(acc0[r] + bb));
        hb[(32 * mh + 16 + 4 * q + r) * 40 + 16 * nh + l15] = f2fp8(gelu_fast(acc1[r] + bb));
      }
      __syncthreads();                          // h[ch&1] complete
      __builtin_amdgcn_s_setprio(1);
      #pragma unroll
      for (int Mt = 0; Mt < 4; ++Mt) {
        long aH = *(const long*)(hb + (16 * Mt + l15) * 40 + q * 8);
        #pragma unroll
        for (int jt = 0; jt < 4; ++jt)
          z[jt][Mt] = __builtin_amdgcn_mfma_f32_16x16x32_fp8_fp8(aH, w2r[jt], z[jt][Mt], 0, 0, 0);
      }
      __builtin_amdgcn_s_setprio(0);
      if (ch < 31) {
        #pragma unroll
        for (int k8 = 0; k8 < 8; ++k8) w1r[k8] = w1n[k8];
      }
    }

    // epilogue: delta = (z+b2)*gamma -> s_del [c][72] -> ybuf in place
    #pragma unroll
    for (int jt = 0; jt < 4; ++jt) {
      int c = wv * 64 + jt * 16 + l15;
      float bb = b2v[c], gm = gammav[c];
      #pragma unroll
      for (int Mt = 0; Mt < 4; ++Mt) {
        #pragma unroll
        for (int r = 0; r < 4; ++r)
          s_del[c * 72 + 16 * Mt + 4 * q + r] = f2bf((z[jt][Mt][r] + bb) * gm);
      }
    }
    __syncthreads();
    #pragma unroll
    for (int k = 0; k < 8; ++k) {
      int q4 = tid + 256 * k;
      int c = q4 & 255, pd = (q4 >> 8) * 8;
      bf16x8 v = *(const bf16x8*)(s_del + c * 72 + pd);
      *(bf16x8*)(ytile + c * 64 + pd) = v;
    }
    __syncthreads();                            // s_del reads done before next
  }
}

// ---------------------------------------------------------------------------
// epi_k: dense, fully coalesced. out = x + (active ? delta : 0).
// ---------------------------------------------------------------------------
__global__ __launch_bounds__(256) void epi_k(
    const float* __restrict__ x, const int* __restrict__ mask,
    const short* __restrict__ delta, float* __restrict__ out) {
  const int NU = 32 * DIMC * HW * 7;            // units of 8 floats
  int stride = gridDim.x * 256;
  for (int u = blockIdx.x * 256 + threadIdx.x; u < NU; u += stride) {
    int wb = u % 7; int t1 = u / 7;
    int h = t1 % 56; int t2 = t1 / 56;
    int c = t2 & 255; int b = t2 >> 8;
    int g = ((b * DIMC + c) * HW + h) * HW + wb * 8;
    f32x4 x0 = *(const f32x4*)(x + g);
    f32x4 x1 = *(const f32x4*)(x + g + 4);
    int tile = (b * 7 + (h >> 3)) * 7 + wb;
    if (mask[tile]) {
      bf16x8 d = *(const bf16x8*)(delta + ((long)tile * DIMC + c) * 64 + (h & 7) * 8);
      #pragma unroll
      for (int i = 0; i < 4; ++i) { x0[i] += bf2f(d[i]); x1[i] += bf2f(d[4 + i]); }
    }
    *(f32x4*)(out + g) = x0;
    *(f32x4*)(out + g + 4) = x1;
  }
}

extern "C" void kernel_launch(void* const* d_in, const int* in_sizes, int n_in,
                              void* d_out, int out_size, void* d_ws, size_t ws_size,
                              hipStream_t stream) {
  const float* x    = (const float*)d_in[0];
  const int*   mask = (const int*)d_in[1];
  const float* dw_w = (const float*)d_in[2];
  const float* dw_b = (const float*)d_in[3];
  const float* ln_w = (const float*)d_in[4];
  const float* ln_b = (const float*)d_in[5];
  const float* w1   = (const float*)d_in[6];
  const float* b1   = (const float*)d_in[7];
  const float* w2   = (const float*)d_in[8];
  const float* b2   = (const float*)d_in[9];
  const float* gm   = (const float*)d_in[10];
  float* out = (float*)d_out;

  long* w1p  = (long*)d_ws;                     // 256 KB (512 frags x 512B)
  long* w2p  = w1p + 512 * 64;                  // 256 KB
  int*  qmeta = (int*)(w2p + 512 * 64);         // 8 KB: counters + tile list
  short* ybuf = (short*)((char*)qmeta + 8192);  // 51.4 MB

  prep_pack<<<256, 256, 0, stream>>>(w1, w2, w1p, w2p, qmeta);
  compact_k<<<7, 256, 0, stream>>>(mask, qmeta);
  conv_k<<<8192, 256, 0, stream>>>(x, mask, dw_w, dw_b, ybuf);
  mlp_k<<<768, 256, 0, stream>>>(ln_w, ln_b, b1, b2, gm, w1p, w2p, qmeta, ybuf);
  epi_k<<<4096, 256, 0, stream>>>(x, mask, ybuf, out);
}